// Round 20
// baseline (278.230 us; speedup 1.0000x reference)
//
#include <hip/hip_runtime.h>
#include <math.h>

#define NN 50          // neighbours
#define DD 128         // embedding dim
#define KT 4           // 4 k-tiles of 32 (K=128)
#define NIT 128        // b's per block (grid = 256 = 1 block/CU, one round)
#define TILE_H 12800   // 50 rows * 256 B (fp16 tile)
#define NSLOT 4        // ring depth (51.2 KB)

typedef __attribute__((ext_vector_type(4))) float  f32x4;
typedef __attribute__((ext_vector_type(2))) __fp16 f16x2;   // cvt_pkrtz return type
typedef __attribute__((ext_vector_type(4))) __fp16 f16x4;
typedef __attribute__((ext_vector_type(8))) __fp16 f16x8;

// fp32 scratch for W@A1 / W@A2, then fp16 transposed weight tables.
__device__ float g_WA1f[DD * DD];
__device__ float g_WA2f[DD * DD];
__device__ __attribute__((aligned(16))) __fp16 g_Wt[2 * DD * DD];  // [col 0..255][k]: [W | W@A2]^T
__device__ __attribute__((aligned(16))) __fp16 g_W1t[DD * DD];     // [col d][k]     : (W@A1)^T

__global__ void compute_WA(const float* __restrict__ W,
                           const float* __restrict__ A_w) {
    const int d = threadIdx.x, k = blockIdx.x, m = blockIdx.y;
    const float* __restrict__ A = A_w + (size_t)m * DD * DD;
    float acc = 0.f;
#pragma unroll 8
    for (int j = 0; j < DD; ++j)
        acc = fmaf(W[k * DD + j], A[j * DD + d], acc);
    if (m == 0) g_WA1f[k * DD + d] = acc;
    else        g_WA2f[k * DD + d] = acc;
}

__global__ void cvt_weights(const float* __restrict__ W) {
    const int n = blockIdx.x;      // 0..383
    const int k = threadIdx.x;     // 0..127
    if (n < DD)          g_Wt[n * DD + k]             = (__fp16)W[k * DD + n];
    else if (n < 2 * DD) g_Wt[n * DD + k]             = (__fp16)g_WA2f[k * DD + (n - DD)];
    else                 g_W1t[(n - 2 * DD) * DD + k] = (__fp16)g_WA1f[k * DD + (n - 2 * DD)];
}

// 8 consecutive fp32 -> 8 fp16 (packed RTZ converts, 4 instrs)
__device__ __forceinline__ f16x8 cvt8(float4 f0, float4 f1) {
    union { f16x2 h[4]; f16x8 v; } u;
    u.h[0] = __builtin_amdgcn_cvt_pkrtz(f0.x, f0.y);
    u.h[1] = __builtin_amdgcn_cvt_pkrtz(f0.z, f0.w);
    u.h[2] = __builtin_amdgcn_cvt_pkrtz(f1.x, f1.y);
    u.h[3] = __builtin_amdgcn_cvt_pkrtz(f1.z, f1.w);
    return u.v;
}

#define MFMA(a, b, c) __builtin_amdgcn_mfma_f32_16x16x32_f16((a), (b), (c), 0, 0, 0)

// v20: PRODUCER-CONSUMER wave specialization — removes the block barrier that
// made r10-r19's phases SUM (closed budget 7870 cy ~ measured). 8 waves:
// w0-3 = producers (HBM->reg->LDS ring, free-running, private reg deps so no
// shared vmcnt discipline), w4-7 = consumers (32 cols each: bF 64 + acc 64
// regs; full softmax per wave, NO cross-wave combine). Sync = LDS counters
// ready[]/done[] + polling (cumulative, no reset races; re-init per launch).
// Producer: lgkmcnt(0) before ready++. Consumer: lgkmcnt(0) after last read,
// done++, THEN softmax/store while producer overwrites the slot.
// 1 block/CU (117 KB LDS), launch_bounds(512,2) -> 256-VGPR cap, no spill.
__global__ __launch_bounds__(512, 2)
void attn_mfma(const float* __restrict__ x,
               const float* __restrict__ nbr,
               const float* __restrict__ A_b,
               float* __restrict__ out, int B) {
    __shared__ __attribute__((aligned(16))) char slots[NSLOT][TILE_H]; // 51.2 KB
    __shared__ float pxa_lds[NIT][DD];                                 // 65.5 KB
    __shared__ int readyf[NSLOT], donef[NSLOT];

    const int tid  = threadIdx.x;
    const int w    = tid >> 6;     // 0..7
    const int lane = tid & 63;
    const int c    = lane & 15;    // A-row / B-col / D-col lane index
    const int g    = lane >> 4;    // k-group / D-row group
    const size_t b0 = (size_t)blockIdx.x * NIT;

    if (tid < NSLOT) { readyf[tid] = 0; donef[tid] = 0; }

    // ---- Phase A (all 8 waves): pxa_lds[i][16w+c] = A_b + (x[b0+i]@WA1) ----
    {
        const int pcol = 16 * w + c;
        f32x4 pacc[NIT / 16];
#pragma unroll
        for (int mt = 0; mt < NIT / 16; ++mt) pacc[mt] = (f32x4)0.f;
#pragma unroll
        for (int mt = 0; mt < NIT / 16; ++mt) {
            long brow = (long)b0 + 16 * mt + c;
            if (brow > B - 1) brow = B - 1;
            const float4* __restrict__ xp =
                reinterpret_cast<const float4*>(x + brow * DD);
#pragma unroll
            for (int kt = 0; kt < KT; ++kt) {
                const f16x8 a = cvt8(xp[8 * kt + 2 * g], xp[8 * kt + 2 * g + 1]);
                const f16x8 bw = *reinterpret_cast<const f16x8*>(
                    g_W1t + pcol * DD + 32 * kt + 8 * g);
                pacc[mt] = MFMA(a, bw, pacc[mt]);
            }
        }
        const float ab = A_b[pcol];
#pragma unroll
        for (int mt = 0; mt < NIT / 16; ++mt)
#pragma unroll
            for (int r = 0; r < 4; ++r)
                pxa_lds[16 * mt + 4 * g + r][pcol] = pacc[mt][r] + ab;
    }
    __syncthreads();   // pxa + flags visible; the ONLY block barrier

    if (w < 4) {
        // ================= PRODUCER (waves 0-3) =================
        f32x4 raA[7], raB[7];      // ping-pong staging, 56 VGPRs

        auto load_tile = [&](f32x4 (&ra)[7], int it) {
            size_t bidx = b0 + (size_t)(it < NIT ? it : NIT - 1);
            if (bidx > (size_t)(B - 1)) bidx = (size_t)(B - 1);
            const f32x4* __restrict__ nb4 =
                reinterpret_cast<const f32x4*>(nbr + bidx * (size_t)(NN * DD));
#pragma unroll
            for (int j = 0; j < 7; ++j) {
                const int p = w + 4 * j;          // chunks w, w+4, ..., w+24
                if (p < 25)
                    ra[j] = __builtin_nontemporal_load(nb4 + p * 64 + lane);
            }
        };
        auto write_tile = [&](f32x4 (&ra)[7], char* dst) {
#pragma unroll
            for (int j = 0; j < 7; ++j) {
                const int p = w + 4 * j;
                if (p < 25) {
                    const int lb  = p * 512 + lane * 8;   // fp16-tile byte off
                    const int row = lb >> 8;
                    const int ad  = lb ^ ((row & 7) << 4);
                    union { f16x2 h[2]; f16x4 v; } u;
                    u.h[0] = __builtin_amdgcn_cvt_pkrtz(ra[j][0], ra[j][1]);
                    u.h[1] = __builtin_amdgcn_cvt_pkrtz(ra[j][2], ra[j][3]);
                    *reinterpret_cast<f16x4*>(dst + ad) = u.v;  // ds_write_b64
                }
            }
        };

        load_tile(raA, 0);
#pragma unroll 1
        for (int t = 0; t < NIT; ++t) {
            const int s = t & (NSLOT - 1);
            const int e = t >> 2;              // epoch
            // issue NEXT tile's loads before polling (HBM busy during wait)
            if (t + 1 < NIT) load_tile((t & 1) ? raA : raB, t + 1);
            // wait: consumers finished epoch e-1 on this slot (done == 4e)
            while (*(volatile int*)&donef[s] < 4 * e)
                __builtin_amdgcn_s_sleep(2);
            asm volatile("" ::: "memory");
            write_tile((t & 1) ? raB : raA, slots[s]);
            asm volatile("s_waitcnt lgkmcnt(0)" ::: "memory");  // writes landed
            if (lane == 0) atomicAdd(&readyf[s], 1);
        }
    } else {
        // ================= CONSUMER (waves 4-7) =================
        const int cg = w - 4;      // col-group: cols 32cg .. 32cg+31

        f16x8 bF[2][2][KT];        // 64 VGPRs, pinned
#pragma unroll
        for (int p = 0; p < 2; ++p)
#pragma unroll
            for (int nt = 0; nt < 2; ++nt)
#pragma unroll
                for (int kt = 0; kt < KT; ++kt) {
                    const int colx = p * DD + 32 * cg + 16 * nt + c;
                    bF[p][nt][kt] = *reinterpret_cast<const f16x8*>(
                        g_Wt + colx * DD + 32 * kt + 8 * g);
                    asm volatile("" : "+v"(bF[p][nt][kt]));
                }

        const float m0v = (g == 0) ? 1.f : 0.f;  // rows 48,49 (mt=3, r<2)

#pragma unroll 1
        for (int t = 0; t < NIT; ++t) {
            const int s = t & (NSLOT - 1);
            const int e = t >> 2;
            // wait: all 4 producers filled this slot for epoch e
            while (*(volatile int*)&readyf[s] < 4 * (e + 1))
                __builtin_amdgcn_s_sleep(2);
            asm volatile("" ::: "memory");

            const char* __restrict__ tile = slots[s];
            f32x4 acc[4][2][2];    // [mt][p][nt], 64 VGPRs
#pragma unroll
            for (int mt = 0; mt < 4; ++mt)
#pragma unroll
                for (int p = 0; p < 2; ++p)
#pragma unroll
                    for (int nt = 0; nt < 2; ++nt) acc[mt][p][nt] = (f32x4)0.f;

            __builtin_amdgcn_s_setprio(1);
#pragma unroll
            for (int mt = 0; mt < 4; ++mt) {
                int row = 16 * mt + c;
                if (row > NN - 1) row = NN - 1;   // pad rows masked below
                const int rb = row * 256;
                const int sw = (row & 7) << 4;
#pragma unroll
                for (int kt = 0; kt < KT; ++kt) {
                    const f16x8 a = *reinterpret_cast<const f16x8*>(
                        tile + ((rb + kt * 64 + g * 16) ^ sw));
#pragma unroll
                    for (int p = 0; p < 2; ++p)
#pragma unroll
                        for (int nt = 0; nt < 2; ++nt)
                            acc[mt][p][nt] = MFMA(a, bF[p][nt][kt], acc[mt][p][nt]);
                }
            }
            __builtin_amdgcn_s_setprio(0);

            // reads retired -> release the slot BEFORE softmax/store
            asm volatile("s_waitcnt lgkmcnt(0)" ::: "memory");
            __builtin_amdgcn_sched_barrier(0);
            if (lane == 0) atomicAdd(&donef[s], 1);

            // softmax over n for this wave's 32 cols (no max-shift)
#pragma unroll
            for (int nt = 0; nt < 2; ++nt) {
                const float pxa = pxa_lds[t][32 * cg + 16 * nt + c];
                float den = 0.f, num = 0.f;
#pragma unroll
                for (int mt = 0; mt < 4; ++mt)
#pragma unroll
                    for (int r = 0; r < 4; ++r) {
                        if (mt == 3 && r >= 2) continue;   // n >= 52
                        float tt = pxa + acc[mt][1][nt][r];
                        tt = fmaxf(tt, 0.2f * tt);         // leaky_relu(0.2)
                        float pp = __expf(tt);
                        if (mt == 3) pp *= m0v;            // n=48,49 iff g==0
                        den += pp;
                        num = fmaf(pp, acc[mt][0][nt][r], num);
                    }
                den += __shfl_xor(den, 16); den += __shfl_xor(den, 32);
                num += __shfl_xor(num, 16); num += __shfl_xor(num, 32);
                if (g == 0 && b0 + t < (size_t)B)
                    __builtin_nontemporal_store(__fdividef(num, den),
                        out + (b0 + t) * DD + 32 * cg + 16 * nt + c);
            }
        }
    }
}

extern "C" void kernel_launch(void* const* d_in, const int* in_sizes, int n_in,
                              void* d_out, int out_size, void* d_ws, size_t ws_size,
                              hipStream_t stream) {
    const float* x   = (const float*)d_in[0];  // [B, D]
    const float* nbr = (const float*)d_in[1];  // [B, N, D]
    const float* W   = (const float*)d_in[2];  // [D, D]
    const float* A_w = (const float*)d_in[3];  // [2D, D]
    const float* A_b = (const float*)d_in[4];  // [D]
    float* out = (float*)d_out;                // [B, D]
    const int B = in_sizes[0] / DD;

    compute_WA<<<dim3(DD, 2), DD, 0, stream>>>(W, A_w);
    cvt_weights<<<3 * DD, DD, 0, stream>>>(W);
    const int grid = (B + NIT - 1) / NIT;      // 256 blocks = 1/CU, one round
    attn_mfma<<<grid, 512, 0, stream>>>(x, nbr, A_b, out, B);
}

// Round 21
// 209.773 us; speedup vs baseline: 1.3263x; 1.3263x over previous
//
#include <hip/hip_runtime.h>
#include <math.h>

#define NN 50          // neighbours
#define DD 128         // embedding dim
#define MT 4           // 4 m-tiles of 16 rows (50 padded to 64)
#define KT 4           // 4 k-tiles of 32 (K=128)
#define NIT 64         // b's per block  (grid = B/NIT = 512 = 2 blocks/CU)
#define TILE_H 12800   // 50 rows * 256 B (fp16 tile)

typedef __attribute__((ext_vector_type(4))) float  f32x4;
typedef __attribute__((ext_vector_type(2))) __fp16 f16x2;   // cvt_pkrtz return type
typedef __attribute__((ext_vector_type(4))) __fp16 f16x4;
typedef __attribute__((ext_vector_type(8))) __fp16 f16x8;

// fp32 scratch for W@A1 / W@A2, then fp16 transposed weight tables.
__device__ float g_WA1f[DD * DD];
__device__ float g_WA2f[DD * DD];
__device__ __attribute__((aligned(16))) __fp16 g_Wt[2 * DD * DD];  // [col 0..255][k]: [W | W@A2]^T
__device__ __attribute__((aligned(16))) __fp16 g_W1t[DD * DD];     // [col d][k]     : (W@A1)^T

__global__ void compute_WA(const float* __restrict__ W,
                           const float* __restrict__ A_w) {
    const int d = threadIdx.x, k = blockIdx.x, m = blockIdx.y;
    const float* __restrict__ A = A_w + (size_t)m * DD * DD;
    float acc = 0.f;
#pragma unroll 8
    for (int j = 0; j < DD; ++j)
        acc = fmaf(W[k * DD + j], A[j * DD + d], acc);
    if (m == 0) g_WA1f[k * DD + d] = acc;
    else        g_WA2f[k * DD + d] = acc;
}

__global__ void cvt_weights(const float* __restrict__ W) {
    const int n = blockIdx.x;      // 0..383
    const int k = threadIdx.x;     // 0..127
    if (n < DD)          g_Wt[n * DD + k]             = (__fp16)W[k * DD + n];
    else if (n < 2 * DD) g_Wt[n * DD + k]             = (__fp16)g_WA2f[k * DD + (n - DD)];
    else                 g_W1t[(n - 2 * DD) * DD + k] = (__fp16)g_WA1f[k * DD + (n - 2 * DD)];
}

// 8 consecutive fp32 -> 8 fp16 (packed RTZ converts, 4 instrs)
__device__ __forceinline__ f16x8 cvt8(float4 f0, float4 f1) {
    union { f16x2 h[4]; f16x8 v; } u;
    u.h[0] = __builtin_amdgcn_cvt_pkrtz(f0.x, f0.y);
    u.h[1] = __builtin_amdgcn_cvt_pkrtz(f0.z, f0.w);
    u.h[2] = __builtin_amdgcn_cvt_pkrtz(f1.x, f1.y);
    u.h[3] = __builtin_amdgcn_cvt_pkrtz(f1.z, f1.w);
    return u.v;
}

#define MFMA(a, b, c) __builtin_amdgcn_mfma_f32_16x16x32_f16((a), (b), (c), 0, 0, 0)

// v21 = r17 exactly (best: 209 us, absmax 1.56e-2). Final kernel.
// Structure: reg-staged 2-deep pipeline, 512 thr / 8 waves / 16 cols per
// wave, <=128 VGPR -> 4 waves/SIMD, 2 blocks/CU; fp16 LDS tile with XOR
// swizzle; split load issue; deferred out-store; no-max-shift softmax.
// Probe record (r10-r20): DMA staging, 3-deep pipe, 2-tile periods, column
// split, direct-reg A, softmax placement, nt loads, split issue, deferred
// store, row-split, phase stagger, producer-consumer — all neutral or
// regressions vs this. Serial budget closes: HBM 5018 + LDS 1500 + VALU
// 1100 + sync ~ 7850 cy/iter measured.
__global__ __launch_bounds__(512, 4)
void attn_mfma(const float* __restrict__ x,
               const float* __restrict__ nbr,
               const float* __restrict__ A_b,
               float* __restrict__ out, int B) {
    __shared__ __attribute__((aligned(16))) char tiles[2][TILE_H];  // 25.6 KB
    __shared__ float pxa_lds[NIT][DD];                              // 32.8 KB

    const int tid  = threadIdx.x;
    const int w    = tid >> 6;     // 0..7
    const int lane = tid & 63;
    const int c    = lane & 15;    // A-row / B-col / D-col lane index
    const int g    = lane >> 4;    // k-group / D-row group
    const size_t b0 = (size_t)blockIdx.x * NIT;
    const int col  = 16 * w + c;   // this wave's output column

    // ---- Phase A: pxa_lds[i][col] = A_b[col] + (x[b0+i] @ WA1)[col] ----
    {
        f32x4 pacc[MT];
#pragma unroll
        for (int mt = 0; mt < MT; ++mt) pacc[mt] = (f32x4)0.f;
#pragma unroll
        for (int mt = 0; mt < MT; ++mt) {
            long brow = (long)b0 + 16 * mt + c;
            if (brow > B - 1) brow = B - 1;
            const float4* __restrict__ xp =
                reinterpret_cast<const float4*>(x + brow * DD);
#pragma unroll
            for (int kt = 0; kt < KT; ++kt) {
                const f16x8 a = cvt8(xp[8 * kt + 2 * g], xp[8 * kt + 2 * g + 1]);
                const f16x8 bw = *reinterpret_cast<const f16x8*>(
                    g_W1t + col * DD + 32 * kt + 8 * g);
                pacc[mt] = MFMA(a, bw, pacc[mt]);
            }
        }
        const float ab = A_b[col];
#pragma unroll
        for (int mt = 0; mt < MT; ++mt)
#pragma unroll
            for (int r = 0; r < 4; ++r)
                pxa_lds[16 * mt + 4 * g + r][col] = pacc[mt][r] + ab;
    }

    // ---- B fragments (this wave's 16 cols, parts W and WA2), pinned ----
    f16x8 bF[2][KT];               // 32 VGPRs
#pragma unroll
    for (int p = 0; p < 2; ++p)
#pragma unroll
        for (int kt = 0; kt < KT; ++kt) {
            bF[p][kt] = *reinterpret_cast<const f16x8*>(
                g_Wt + (p * DD + col) * DD + 32 * kt + 8 * g);
            asm volatile("" : "+v"(bF[p][kt]));   // no remat/sink
        }

    // ---- staging registers: wave's share of one tile (<=4 chunks) ----
    f32x4 ra[4];                   // 16 VGPRs

    auto nb4_of = [&](int it) {
        int itc = it < NIT ? it : NIT - 1;        // tail: harmless re-load
        size_t bidx = b0 + (size_t)itc;
        if (bidx > (size_t)(B - 1)) bidx = (size_t)(B - 1);
        return reinterpret_cast<const f32x4*>(nbr + bidx * (size_t)(NN * DD));
    };
    // half 0: chunks w, w+8 ; half 1: chunks w+16, w+24
    auto load_half = [&](int it, int hf) {
        const f32x4* __restrict__ nb4 = nb4_of(it);
#pragma unroll
        for (int j = 2 * hf; j < 2 * hf + 2; ++j) {
            const int p = w + 8 * j;
            if (p < 25)                           // nt: no L3 allocation
                ra[j] = __builtin_nontemporal_load(nb4 + p * 64 + lane);
        }
    };

    // fp16 tile row = 256 B; byte addr XOR-swizzled by ((row&7)<<4).
    auto write_tile = [&](char* dst) {
#pragma unroll
        for (int j = 0; j < 4; ++j) {
            const int p = w + 8 * j;
            if (p < 25) {
                const int lb  = p * 512 + lane * 8;   // fp16-tile byte offset
                const int row = lb >> 8;
                const int ad  = lb ^ ((row & 7) << 4);
                union { f16x2 h[2]; f16x4 v; } u;
                u.h[0] = __builtin_amdgcn_cvt_pkrtz(ra[j][0], ra[j][1]);
                u.h[1] = __builtin_amdgcn_cvt_pkrtz(ra[j][2], ra[j][3]);
                *reinterpret_cast<f16x4*>(dst + ad) = u.v;   // ds_write_b64
            }
        }
    };

    // one compute half: m-tiles mt0..mt0+1 accumulated into acc
    auto compute_half = [&](const char* tile, f32x4 (&acc)[MT][2], int mt0) {
#pragma unroll
        for (int mt = mt0; mt < mt0 + 2; ++mt) {
            int row = 16 * mt + c;
            if (row > NN - 1) row = NN - 1;  // pad rows masked in softmax
            const int rb = row * 256;
            const int sw = (row & 7) << 4;
#pragma unroll
            for (int kt = 0; kt < KT; ++kt) {
                const f16x8 a = *reinterpret_cast<const f16x8*>(
                    tile + ((rb + kt * 64 + g * 16) ^ sw));
                acc[mt][0] = MFMA(a, bF[0][kt], acc[mt][0]);
                acc[mt][1] = MFMA(a, bF[1][kt], acc[mt][1]);
            }
        }
    };

    // ---- prologue: tile0 -> LDS, tile1 -> regs ----
    load_half(0, 0); load_half(0, 1);
    write_tile(tiles[0]);          // compiler inserts exact vmcnt for ra
    load_half(1, 0); load_half(1, 1);
    asm volatile("s_waitcnt lgkmcnt(0)" ::: "memory");
    __builtin_amdgcn_sched_barrier(0);
    __builtin_amdgcn_s_barrier();  // tiles[0] + pxa_lds visible to all waves

    const float m0v = (g == 0) ? 1.f : 0.f;  // rows 48,49 valid iff g==0 (mt=3,r<2)

    float sNum = 0.f, sDen = 1.f;  // deferred-store carry (tile i-1's result)

#pragma unroll 1
    for (int i = 0; i < NIT; ++i) {
        // (a) regs (tile i+1) -> LDS buf[(i+1)&1]
        write_tile(tiles[(i + 1) & 1]);

        // (a') DEFERRED STORE of tile i-1's result: issued here, ~one full
        // iteration before the next vmcnt-gated point -> commit never stalls.
        if (i > 0 && g == 0)
            __builtin_nontemporal_store(__fdividef(sNum, sDen),
                                        out + (b0 + i - 1) * DD + col);

        // (b1) first half of tile i+2's loads
        load_half(i + 2, 0);
        __builtin_amdgcn_sched_barrier(0);   // pin issue ABOVE compute half 1

        const char* __restrict__ tile = tiles[i & 1];
        f32x4 acc[MT][2];
#pragma unroll
        for (int mt = 0; mt < MT; ++mt)
#pragma unroll
            for (int p = 0; p < 2; ++p) acc[mt][p] = (f32x4)0.f;

        // (c1) compute half 1 (mt 0,1)
        compute_half(tile, acc, 0);

        // (b2) second half of tile i+2's loads — mid-iteration issue point
        load_half(i + 2, 1);
        __builtin_amdgcn_sched_barrier(0);   // pin issue ABOVE compute half 2

        // (c2) compute half 2 (mt 2,3)
        compute_half(tile, acc, 2);

        // softmax over n for this wave's col (no max-shift: logits ~N(0,1.4))
        {
            const float pxa = pxa_lds[i][col];
            float den = 0.f, num = 0.f;
#pragma unroll
            for (int mt = 0; mt < MT; ++mt)
#pragma unroll
                for (int r = 0; r < 4; ++r) {
                    if (mt == 3 && r >= 2) continue;     // n >= 52: never valid
                    float t = pxa + acc[mt][1][r];
                    t = fmaxf(t, 0.2f * t);              // leaky_relu(0.2)
                    float p = __expf(t);
                    if (mt == 3) p *= m0v;               // n=48,49 valid iff g==0
                    den += p;
                    num = fmaf(p, acc[mt][0][r], num);
                }
            den += __shfl_xor(den, 16); den += __shfl_xor(den, 32);
            num += __shfl_xor(num, 16); num += __shfl_xor(num, 32);
            sNum = num; sDen = den;          // carry; stored next iteration
        }

        // (d) all LDS ops done before any wave rewrites buffers next iter
        asm volatile("s_waitcnt lgkmcnt(0)" ::: "memory");
        __builtin_amdgcn_sched_barrier(0);
        __builtin_amdgcn_s_barrier();
    }

    // epilogue: store the last tile's result
    if (g == 0)
        __builtin_nontemporal_store(__fdividef(sNum, sDen),
                                    out + (b0 + NIT - 1) * DD + col);
}

extern "C" void kernel_launch(void* const* d_in, const int* in_sizes, int n_in,
                              void* d_out, int out_size, void* d_ws, size_t ws_size,
                              hipStream_t stream) {
    const float* x   = (const float*)d_in[0];  // [B, D]
    const float* nbr = (const float*)d_in[1];  // [B, N, D]
    const float* W   = (const float*)d_in[2];  // [D, D]
    const float* A_w = (const float*)d_in[3];  // [2D, D]
    const float* A_b = (const float*)d_in[4];  // [D]
    float* out = (float*)d_out;                // [B, D]
    const int B = in_sizes[0] / DD;

    compute_WA<<<dim3(DD, 2), DD, 0, stream>>>(W, A_w);
    cvt_weights<<<3 * DD, DD, 0, stream>>>(W);
    const int grid = (B + NIT - 1) / NIT;      // 512 blocks = 2/CU, one round
    attn_mfma<<<grid, 512, 0, stream>>>(x, nbr, A_b, out, B);
}